// Round 10
// baseline (275.414 us; speedup 1.0000x reference)
//
#include <hip/hip_runtime.h>
#include <hip/hip_bf16.h>

// MHA: weight pre-convert -> fused qkv proj (128x128 m93-class tile; V
// transposed per-head) -> flash attention (transposed-S, fixed-shift log2
// softmax, ones-MFMA denominator) -> out proj (128x128).
// R10: GEMMs rewritten to 128x128 tiles (16 MFMA per 8 LDS frag reads, 2x
// density; padded-36 LDS rows kill the 8-way read aliasing). Flash unchanged
// (control).

typedef __attribute__((ext_vector_type(8))) short bf16x8;   // 8 bf16 (MFMA A/B frag)
typedef __attribute__((ext_vector_type(4))) float f32x4;    // MFMA C/D frag

#define SEQ  4096
#define DM   512
#define FPAD 72    // flash LDS row stride (shorts)
#define GPAD 36    // gemm LDS row stride (shorts): l16*18 mod 32 spreads banks
#define QSCALE 0.18033688011112042f   // 0.125 * log2(e): scores in log2 domain
#define FSHIFT 16.0f                  // fixed softmax shift (log2 domain)

__device__ inline float fast_exp2(float x) {   // raw v_exp_f32: D = 2^S0
#if __has_builtin(__builtin_amdgcn_exp2f)
    return __builtin_amdgcn_exp2f(x);
#else
    return __expf(x * 0.69314718056f);
#endif
}

__device__ inline unsigned pk2(float x, float y) {   // 2x f32 -> packed bf16 RNE
#if __has_builtin(__builtin_amdgcn_cvt_pk_bf16_f32)
    typedef __attribute__((ext_vector_type(2))) __bf16 bf16x2_t;
    bf16x2_t h = __builtin_amdgcn_cvt_pk_bf16_f32(x, y);
    return *(unsigned*)&h;
#else
    unsigned ux = __float_as_uint(x);
    unsigned uy = __float_as_uint(y);
    ux += 0x7fff + ((ux >> 16) & 1);      // finite-safe RNE (all inputs finite)
    uy += 0x7fff + ((uy >> 16) & 1);
    return (ux >> 16) | (uy & 0xffff0000u);
#endif
}

// Convert the 4 weight matrices (512x512 fp32) to bf16 once.
__global__ __launch_bounds__(256) void cvt_w(
    const float* __restrict__ w0, const float* __restrict__ w1,
    const float* __restrict__ w2, const float* __restrict__ w3,
    __hip_bfloat16* __restrict__ o0, __hip_bfloat16* __restrict__ o1,
    __hip_bfloat16* __restrict__ o2, __hip_bfloat16* __restrict__ o3)
{
    const float* w = (blockIdx.y == 0) ? w0 : (blockIdx.y == 1) ? w1
                   : (blockIdx.y == 2) ? w2 : w3;
    __hip_bfloat16* o = (blockIdx.y == 0) ? o0 : (blockIdx.y == 1) ? o1
                      : (blockIdx.y == 2) ? o2 : o3;
    const int i = (blockIdx.x * 256 + threadIdx.x) * 4;   // < 262144
    float4 v = *(const float4*)&w[i];
    uint2 p;
    p.x = pk2(v.x, v.y);
    p.y = pk2(v.z, v.w);
    *(uint2*)&((unsigned short*)o)[i] = p;
}

// Fused QKV projection, 128(M) x 128(N) tile, 4 waves 2x2, wave = 64x64.
//   z=0: Q = (x@Wq^T + bq) * QSCALE -> row-major bf16 [8192][512]
//   z=1: K                          -> row-major bf16 [8192][512]
//   z=2: V                          -> transposed per-head: out[(b*512+col)*4096 + seq]
__global__ __launch_bounds__(256) void qkv_proj(
    const float* __restrict__ Xq, const float* __restrict__ Xk, const float* __restrict__ Xv,
    const __hip_bfloat16* __restrict__ Wq16, const __hip_bfloat16* __restrict__ Wk16,
    const __hip_bfloat16* __restrict__ Wv16,
    const float* __restrict__ bq, const float* __restrict__ bk, const float* __restrict__ bv,
    __hip_bfloat16* __restrict__ Oq, __hip_bfloat16* __restrict__ Ok,
    __hip_bfloat16* __restrict__ Ovt)
{
    const int z = blockIdx.z;
    const float* A          = (z == 0) ? Xq : (z == 1) ? Xk : Xv;
    const __hip_bfloat16* W = (z == 0) ? Wq16 : (z == 1) ? Wk16 : Wv16;
    const float* bias       = (z == 0) ? bq : (z == 1) ? bk : bv;

    __shared__ __align__(16) short As[128 * GPAD];   // 9.2 KB
    __shared__ __align__(16) short Ws[128 * GPAD];   // 9.2 KB

    const int bm   = blockIdx.x * 128;
    const int bn   = blockIdx.y * 128;
    const int tid  = threadIdx.x;
    const int wave = tid >> 6;
    const int lane = tid & 63;
    const int quad = lane >> 4;
    const int l16  = lane & 15;
    const int wm   = (wave >> 1) * 64;   // wave row offset in tile
    const int wn   = (wave & 1) * 64;    // wave col offset in tile

    const int srow = tid >> 1;           // 0..127
    const int scol = (tid & 1) * 16;     // 0 / 16 (elements)

    f32x4 acc[4][4] = {};

    // prefetch k-chunk 0
    const float* Ap = &A[(size_t)(bm + srow) * DM + scol];
    const __hip_bfloat16* Wp = &W[(size_t)(bn + srow) * DM + scol];
    float4 a0 = *(const float4*)(Ap + 0);
    float4 a1 = *(const float4*)(Ap + 4);
    float4 a2 = *(const float4*)(Ap + 8);
    float4 a3 = *(const float4*)(Ap + 12);
    bf16x8 w0 = *(const bf16x8*)(Wp + 0);
    bf16x8 w1 = *(const bf16x8*)(Wp + 8);

    for (int k0 = 0; k0 < DM; k0 += 32) {
        uint4 pa0 = {pk2(a0.x, a0.y), pk2(a0.z, a0.w), pk2(a1.x, a1.y), pk2(a1.z, a1.w)};
        uint4 pa1 = {pk2(a2.x, a2.y), pk2(a2.z, a2.w), pk2(a3.x, a3.y), pk2(a3.z, a3.w)};

        __syncthreads();
        *(uint4*)&As[srow * GPAD + scol]     = pa0;
        *(uint4*)&As[srow * GPAD + scol + 8] = pa1;
        *(bf16x8*)&Ws[srow * GPAD + scol]     = w0;
        *(bf16x8*)&Ws[srow * GPAD + scol + 8] = w1;
        __syncthreads();

        if (k0 + 32 < DM) {
            a0 = *(const float4*)(Ap + k0 + 32 + 0);
            a1 = *(const float4*)(Ap + k0 + 32 + 4);
            a2 = *(const float4*)(Ap + k0 + 32 + 8);
            a3 = *(const float4*)(Ap + k0 + 32 + 12);
            w0 = *(const bf16x8*)(Wp + k0 + 32 + 0);
            w1 = *(const bf16x8*)(Wp + k0 + 32 + 8);
        }

        bf16x8 af[4], wf[4];
#pragma unroll
        for (int mt = 0; mt < 4; mt++)
            af[mt] = *(bf16x8*)&As[(wm + mt * 16 + l16) * GPAD + quad * 8];
#pragma unroll
        for (int nt = 0; nt < 4; nt++)
            wf[nt] = *(bf16x8*)&Ws[(wn + nt * 16 + l16) * GPAD + quad * 8];
#pragma unroll
        for (int mt = 0; mt < 4; mt++)
#pragma unroll
            for (int nt = 0; nt < 4; nt++)
                acc[mt][nt] = __builtin_amdgcn_mfma_f32_16x16x32_bf16(
                    af[mt], wf[nt], acc[mt][nt], 0, 0, 0);
    }

    // C/D layout: col = lane&15 (= n), row = quad*4 + r (= m)
    if (z == 2) {
        unsigned short* Vt = (unsigned short*)Ovt;
#pragma unroll
        for (int nt = 0; nt < 4; nt++) {
            const int col = bn + wn + nt * 16 + l16;
            const float bv_ = bias[col];
#pragma unroll
            for (int mt = 0; mt < 4; mt++) {
                const int row0 = bm + wm + mt * 16 + quad * 4;
                const int b    = row0 >> 12;
                const int seq0 = row0 & 4095;
                uint2 pk;
                pk.x = pk2(acc[mt][nt][0] + bv_, acc[mt][nt][1] + bv_);
                pk.y = pk2(acc[mt][nt][2] + bv_, acc[mt][nt][3] + bv_);
                *(uint2*)&Vt[((size_t)(b * 512 + col)) * 4096 + seq0] = pk;
            }
        }
    } else {
        __hip_bfloat16* C = (z == 0) ? Oq : Ok;
        const float scale = (z == 0) ? QSCALE : 1.0f;
#pragma unroll
        for (int nt = 0; nt < 4; nt++) {
            const int col = bn + wn + nt * 16 + l16;
            const float bvs = bias[col] * scale;
#pragma unroll
            for (int mt = 0; mt < 4; mt++) {
                const int row0 = bm + wm + mt * 16 + quad * 4;
#pragma unroll
                for (int r = 0; r < 4; r++)
                    C[(size_t)(row0 + r) * DM + col] =
                        (__hip_bfloat16)__uint_as_float(
                            pk2(acc[mt][nt][r] * scale + bvs, 0.0f) << 16);
            }
        }
    }
}

// Flash attention, transposed-S form, fixed-shift log2 softmax (unchanged R9).
__global__ __launch_bounds__(256) void flash_attn(
    const __hip_bfloat16* __restrict__ Q,
    const __hip_bfloat16* __restrict__ K,
    const __hip_bfloat16* __restrict__ Vt,
    __hip_bfloat16* __restrict__ O)
{
    __shared__ __align__(16) short Qs[64 * FPAD];      // [q][d]; reused as Ps after hoist
    __shared__ __align__(16) short Ks[64 * FPAD];      // [kv][d]
    __shared__ __align__(16) short Vs[64 * FPAD];      // [dv][kv] (pre-transposed)
    short (*Ps)[16 * FPAD] = (short(*)[16 * FPAD])Qs;  // per-wave strip alias

    const int q0 = blockIdx.x * 64;
    const int bh = blockIdx.y;

    const int tid  = threadIdx.x;
    const int wave = tid >> 6;
    const int lane = tid & 63;
    const int quad = lane >> 4;
    const int l16  = lane & 15;

    const __hip_bfloat16* Qb = Q + (size_t)(bh >> 3) * SEQ * DM + (bh & 7) * 64;
    const __hip_bfloat16* Kb = K + (size_t)(bh >> 3) * SEQ * DM + (bh & 7) * 64;
    const __hip_bfloat16* Vb = Vt + (size_t)bh * 64 * SEQ;
    __hip_bfloat16*       Ob = O + (size_t)(bh >> 3) * SEQ * DM + (bh & 7) * 64;

    const int r0 = tid >> 3;        // 0..31 (covers rows r0 and r0+32)
    const int c8 = (tid & 7) * 8;

    *(bf16x8*)&Qs[r0 * FPAD + c8] =
        *(const bf16x8*)&Qb[(size_t)(q0 + r0) * DM + c8];
    *(bf16x8*)&Qs[(r0 + 32) * FPAD + c8] =
        *(const bf16x8*)&Qb[(size_t)(q0 + r0 + 32) * DM + c8];

    bf16x8 kp0 = *(const bf16x8*)&Kb[(size_t)r0 * DM + c8];
    bf16x8 kp1 = *(const bf16x8*)&Kb[(size_t)(r0 + 32) * DM + c8];
    bf16x8 vp0 = *(const bf16x8*)&Vb[(size_t)r0 * SEQ + c8];
    bf16x8 vp1 = *(const bf16x8*)&Vb[(size_t)(r0 + 32) * SEQ + c8];

    __syncthreads();   // Qs staged

    const bf16x8 bq0 = *(bf16x8*)&Qs[(wave * 16 + l16) * FPAD + quad * 8];
    const bf16x8 bq1 = *(bf16x8*)&Qs[(wave * 16 + l16) * FPAD + 32 + quad * 8];

    bf16x8 ones;
#pragma unroll
    for (int j = 0; j < 8; j++) ones[j] = (short)0x3F80;

    f32x4 oacc[4] = {};   // O^T: lane holds (dv = dt*16+quad*4+r, q = l16)
    f32x4 lacc = {};      // lacc[*] = l for q = l16

    for (int kv0 = 0; kv0 < SEQ; kv0 += 64) {
        __syncthreads();
        *(bf16x8*)&Ks[r0 * FPAD + c8] = kp0;
        *(bf16x8*)&Ks[(r0 + 32) * FPAD + c8] = kp1;
        *(bf16x8*)&Vs[r0 * FPAD + c8] = vp0;
        *(bf16x8*)&Vs[(r0 + 32) * FPAD + c8] = vp1;
        __syncthreads();

        if (kv0 + 64 < SEQ) {
            kp0 = *(const bf16x8*)&Kb[(size_t)(kv0 + 64 + r0) * DM + c8];
            kp1 = *(const bf16x8*)&Kb[(size_t)(kv0 + 96 + r0) * DM + c8];
            vp0 = *(const bf16x8*)&Vb[(size_t)r0 * SEQ + kv0 + 64 + c8];
            vp1 = *(const bf16x8*)&Vb[(size_t)(r0 + 32) * SEQ + kv0 + 64 + c8];
        }

        f32x4 s[4] = {};
#pragma unroll
        for (int nt = 0; nt < 4; nt++) {
            bf16x8 ak = *(bf16x8*)&Ks[(nt * 16 + l16) * FPAD + quad * 8];
            s[nt] = __builtin_amdgcn_mfma_f32_16x16x32_bf16(ak, bq0, s[nt], 0, 0, 0);
        }
#pragma unroll
        for (int nt = 0; nt < 4; nt++) {
            bf16x8 ak = *(bf16x8*)&Ks[(nt * 16 + l16) * FPAD + 32 + quad * 8];
            s[nt] = __builtin_amdgcn_mfma_f32_16x16x32_bf16(ak, bq1, s[nt], 0, 0, 0);
        }

        // P = 2^(s - 16): no max, no rescale (exact by shift-invariance)
#pragma unroll
        for (int nt = 0; nt < 4; nt++) {
            float p0 = fast_exp2(s[nt][0] - FSHIFT);
            float p1 = fast_exp2(s[nt][1] - FSHIFT);
            float p2 = fast_exp2(s[nt][2] - FSHIFT);
            float p3 = fast_exp2(s[nt][3] - FSHIFT);
            uint2 pk;
            pk.x = pk2(p0, p1);
            pk.y = pk2(p2, p3);
            *(uint2*)&Ps[wave][l16 * FPAD + nt * 16 + quad * 4] = pk;
        }

        // O^T += V^T P^T; l += ones P^T  (no barrier: Ps strip is per-wave)
#pragma unroll
        for (int ks = 0; ks < 2; ks++) {
            bf16x8 bp = *(bf16x8*)&Ps[wave][l16 * FPAD + ks * 32 + quad * 8];
#pragma unroll
            for (int dt = 0; dt < 4; dt++) {
                bf16x8 av = *(bf16x8*)&Vs[(dt * 16 + l16) * FPAD + ks * 32 + quad * 8];
                oacc[dt] = __builtin_amdgcn_mfma_f32_16x16x32_bf16(av, bp, oacc[dt], 0, 0, 0);
            }
            lacc = __builtin_amdgcn_mfma_f32_16x16x32_bf16(ones, bp, lacc, 0, 0, 0);
        }
    }

    const float inv = 1.0f / lacc[0];
    const int q = q0 + wave * 16 + l16;
    unsigned short* Op = (unsigned short*)Ob;
#pragma unroll
    for (int dt = 0; dt < 4; dt++) {
        uint2 ov;
        ov.x = pk2(oacc[dt][0] * inv, oacc[dt][1] * inv);
        ov.y = pk2(oacc[dt][2] * inv, oacc[dt][3] * inv);
        *(uint2*)&Op[(size_t)q * DM + dt * 16 + quad * 4] = ov;
    }
}

// Output projection, 128x128 tile: A bf16, W bf16 (pre-converted), C fp32.
__global__ __launch_bounds__(256) void out_proj(
    const __hip_bfloat16* __restrict__ A,
    const __hip_bfloat16* __restrict__ W,
    const float* __restrict__ bias,
    float* __restrict__ C)
{
    __shared__ __align__(16) short As[128 * GPAD];
    __shared__ __align__(16) short Ws[128 * GPAD];

    const int bm   = blockIdx.x * 128;
    const int bn   = blockIdx.y * 128;
    const int tid  = threadIdx.x;
    const int wave = tid >> 6;
    const int lane = tid & 63;
    const int quad = lane >> 4;
    const int l16  = lane & 15;
    const int wm   = (wave >> 1) * 64;
    const int wn   = (wave & 1) * 64;

    const int srow = tid >> 1;
    const int scol = (tid & 1) * 16;

    f32x4 acc[4][4] = {};

    const __hip_bfloat16* Ap = &A[(size_t)(bm + srow) * DM + scol];
    const __hip_bfloat16* Wp = &W[(size_t)(bn + srow) * DM + scol];
    bf16x8 a0 = *(const bf16x8*)(Ap + 0);
    bf16x8 a1 = *(const bf16x8*)(Ap + 8);
    bf16x8 w0 = *(const bf16x8*)(Wp + 0);
    bf16x8 w1 = *(const bf16x8*)(Wp + 8);

    for (int k0 = 0; k0 < DM; k0 += 32) {
        __syncthreads();
        *(bf16x8*)&As[srow * GPAD + scol]     = a0;
        *(bf16x8*)&As[srow * GPAD + scol + 8] = a1;
        *(bf16x8*)&Ws[srow * GPAD + scol]     = w0;
        *(bf16x8*)&Ws[srow * GPAD + scol + 8] = w1;
        __syncthreads();

        if (k0 + 32 < DM) {
            a0 = *(const bf16x8*)(Ap + k0 + 32 + 0);
            a1 = *(const bf16x8*)(Ap + k0 + 32 + 8);
            w0 = *(const bf16x8*)(Wp + k0 + 32 + 0);
            w1 = *(const bf16x8*)(Wp + k0 + 32 + 8);
        }

        bf16x8 af[4], wf[4];
#pragma unroll
        for (int mt = 0; mt < 4; mt++)
            af[mt] = *(bf16x8*)&As[(wm + mt * 16 + l16) * GPAD + quad * 8];
#pragma unroll
        for (int nt = 0; nt < 4; nt++)
            wf[nt] = *(bf16x8*)&Ws[(wn + nt * 16 + l16) * GPAD + quad * 8];
#pragma unroll
        for (int mt = 0; mt < 4; mt++)
#pragma unroll
            for (int nt = 0; nt < 4; nt++)
                acc[mt][nt] = __builtin_amdgcn_mfma_f32_16x16x32_bf16(
                    af[mt], wf[nt], acc[mt][nt], 0, 0, 0);
    }

#pragma unroll
    for (int nt = 0; nt < 4; nt++) {
        const int col = bn + wn + nt * 16 + l16;
        const float bv_ = bias[col];
#pragma unroll
        for (int mt = 0; mt < 4; mt++) {
            const int row0 = bm + wm + mt * 16 + quad * 4;
#pragma unroll
            for (int r = 0; r < 4; r++)
                C[(size_t)(row0 + r) * DM + col] = acc[mt][nt][r] + bv_;
        }
    }
}

extern "C" void kernel_launch(void* const* d_in, const int* in_sizes, int n_in,
                              void* d_out, int out_size, void* d_ws, size_t ws_size,
                              hipStream_t stream) {
    const float* queries = (const float*)d_in[0];
    const float* keys    = (const float*)d_in[1];
    const float* values  = (const float*)d_in[2];
    const float* Wq = (const float*)d_in[3];
    const float* bq = (const float*)d_in[4];
    const float* Wk = (const float*)d_in[5];
    const float* bk = (const float*)d_in[6];
    const float* Wv = (const float*)d_in[7];
    const float* bv = (const float*)d_in[8];
    const float* Wo = (const float*)d_in[9];
    const float* bo = (const float*)d_in[10];
    float* out = (float*)d_out;

    const size_t MS = (size_t)2 * SEQ * DM;   // 4.19M elems
    const size_t WN = (size_t)DM * DM;        // 262144 elems
    __hip_bfloat16* q_ws  = (__hip_bfloat16*)d_ws;
    __hip_bfloat16* k_ws  = q_ws + MS;
    __hip_bfloat16* vt_ws = k_ws + MS;        // [16][64][4096]
    __hip_bfloat16* o_ws  = vt_ws + MS;
    __hip_bfloat16* wq16  = o_ws + MS;
    __hip_bfloat16* wk16  = wq16 + WN;
    __hip_bfloat16* wv16  = wk16 + WN;
    __hip_bfloat16* wo16  = wv16 + WN;

    dim3 blk(256);

    cvt_w<<<dim3(256, 4), blk, 0, stream>>>(Wq, Wk, Wv, Wo, wq16, wk16, wv16, wo16);

    qkv_proj<<<dim3(64, 4, 3), blk, 0, stream>>>(
        queries, keys, values, wq16, wk16, wv16, bq, bk, bv, q_ws, k_ws, vt_ws);

    flash_attn<<<dim3(64, 16), blk, 0, stream>>>(q_ws, k_ws, vt_ws, o_ws);

    out_proj<<<dim3(64, 4), blk, 0, stream>>>(o_ws, wo16, bo, out);
}

// Round 11
// 264.259 us; speedup vs baseline: 1.0422x; 1.0422x over previous
//
#include <hip/hip_runtime.h>
#include <hip/hip_bf16.h>

// MHA: weight pre-convert -> fused qkv proj (R9 64x128, measured best; V
// transposed per-head) -> flash attention (transposed-S, fixed-shift log2
// softmax, ones-MFMA denominator, 32 q-rows PER WAVE) -> out proj (R9).
// R11: flash wave owns 32 q (two 16-q column groups) -> Ks/Vs fragments and
// staging shared across both halves: LDS ops per unit work -38%, barriers per
// work halved. GEMMs reverted to R9 (structure-invariant ~131 us; see journal).

typedef __attribute__((ext_vector_type(8))) short bf16x8;   // 8 bf16 (MFMA A/B frag)
typedef __attribute__((ext_vector_type(4))) float f32x4;    // MFMA C/D frag

#define SEQ  4096
#define DM   512
#define FPAD 72    // flash LDS row stride (shorts): min-phase b128 access
#define QSCALE 0.18033688011112042f   // 0.125 * log2(e): scores in log2 domain
#define FSHIFT 16.0f                  // fixed softmax shift (log2 domain)

__device__ inline float fast_exp2(float x) {   // raw v_exp_f32: D = 2^S0
#if __has_builtin(__builtin_amdgcn_exp2f)
    return __builtin_amdgcn_exp2f(x);
#else
    return __expf(x * 0.69314718056f);
#endif
}

__device__ inline unsigned pk2(float x, float y) {   // 2x f32 -> packed bf16 RNE
#if __has_builtin(__builtin_amdgcn_cvt_pk_bf16_f32)
    typedef __attribute__((ext_vector_type(2))) __bf16 bf16x2_t;
    bf16x2_t h = __builtin_amdgcn_cvt_pk_bf16_f32(x, y);
    return *(unsigned*)&h;
#else
    unsigned ux = __float_as_uint(x);
    unsigned uy = __float_as_uint(y);
    ux += 0x7fff + ((ux >> 16) & 1);      // finite-safe RNE (all inputs finite)
    uy += 0x7fff + ((uy >> 16) & 1);
    return (ux >> 16) | (uy & 0xffff0000u);
#endif
}

// Convert the 4 weight matrices (512x512 fp32) to bf16 once.
__global__ __launch_bounds__(256) void cvt_w(
    const float* __restrict__ w0, const float* __restrict__ w1,
    const float* __restrict__ w2, const float* __restrict__ w3,
    __hip_bfloat16* __restrict__ o0, __hip_bfloat16* __restrict__ o1,
    __hip_bfloat16* __restrict__ o2, __hip_bfloat16* __restrict__ o3)
{
    const float* w = (blockIdx.y == 0) ? w0 : (blockIdx.y == 1) ? w1
                   : (blockIdx.y == 2) ? w2 : w3;
    __hip_bfloat16* o = (blockIdx.y == 0) ? o0 : (blockIdx.y == 1) ? o1
                      : (blockIdx.y == 2) ? o2 : o3;
    const int i = (blockIdx.x * 256 + threadIdx.x) * 4;   // < 262144
    float4 v = *(const float4*)&w[i];
    uint2 p;
    p.x = pk2(v.x, v.y);
    p.y = pk2(v.z, v.w);
    *(uint2*)&((unsigned short*)o)[i] = p;
}

// Fused QKV projection (R9 structure), 64(M) x 128(N) tile, z selects stream.
__global__ __launch_bounds__(256) void qkv_proj(
    const float* __restrict__ Xq, const float* __restrict__ Xk, const float* __restrict__ Xv,
    const __hip_bfloat16* __restrict__ Wq16, const __hip_bfloat16* __restrict__ Wk16,
    const __hip_bfloat16* __restrict__ Wv16,
    const float* __restrict__ bq, const float* __restrict__ bk, const float* __restrict__ bv,
    __hip_bfloat16* __restrict__ Oq, __hip_bfloat16* __restrict__ Ok,
    __hip_bfloat16* __restrict__ Ovt)
{
    const int z = blockIdx.z;
    const float* A          = (z == 0) ? Xq : (z == 1) ? Xk : Xv;
    const __hip_bfloat16* W = (z == 0) ? Wq16 : (z == 1) ? Wk16 : Wv16;
    const float* bias       = (z == 0) ? bq : (z == 1) ? bk : bv;

    __shared__ __align__(16) short As[64 * 32];
    __shared__ __align__(16) short Ws2[128 * 32];

    const int bm   = blockIdx.x * 64;
    const int bn   = blockIdx.y * 128;
    const int tid  = threadIdx.x;
    const int wave = tid >> 6;
    const int lane = tid & 63;
    const int quad = lane >> 4;
    const int l16  = lane & 15;

    const int srow = tid >> 2;          // 0..63
    const int scol = (tid & 3) * 8;     // 0/8/16/24

    f32x4 acc[8] = {};

    float4 a0 = *(const float4*)&A[(size_t)(bm + srow) * DM + scol];
    float4 a1 = *(const float4*)&A[(size_t)(bm + srow) * DM + scol + 4];
    bf16x8 w0 = *(const bf16x8*)&W[(size_t)(bn + srow) * DM + scol];
    bf16x8 w1 = *(const bf16x8*)&W[(size_t)(bn + srow + 64) * DM + scol];

    for (int k0 = 0; k0 < DM; k0 += 32) {
        uint4 pa = {pk2(a0.x, a0.y), pk2(a0.z, a0.w), pk2(a1.x, a1.y), pk2(a1.z, a1.w)};

        __syncthreads();
        *(uint4*)&As[srow * 32 + scol] = pa;
        *(bf16x8*)&Ws2[srow * 32 + scol] = w0;
        *(bf16x8*)&Ws2[(srow + 64) * 32 + scol] = w1;
        __syncthreads();

        if (k0 + 32 < DM) {
            a0 = *(const float4*)&A[(size_t)(bm + srow) * DM + k0 + 32 + scol];
            a1 = *(const float4*)&A[(size_t)(bm + srow) * DM + k0 + 32 + scol + 4];
            w0 = *(const bf16x8*)&W[(size_t)(bn + srow) * DM + k0 + 32 + scol];
            w1 = *(const bf16x8*)&W[(size_t)(bn + srow + 64) * DM + k0 + 32 + scol];
        }

        bf16x8 a = *(bf16x8*)&As[(wave * 16 + l16) * 32 + quad * 8];
#pragma unroll
        for (int nt = 0; nt < 8; nt++) {
            bf16x8 b = *(bf16x8*)&Ws2[(nt * 16 + l16) * 32 + quad * 8];
            acc[nt] = __builtin_amdgcn_mfma_f32_16x16x32_bf16(a, b, acc[nt], 0, 0, 0);
        }
    }

    // C/D layout: col = lane&15 (= n), row = quad*4 + r (= m)
    if (z == 2) {
        const int row0 = bm + wave * 16 + quad * 4;
        const int b    = row0 >> 12;
        const int seq0 = row0 & 4095;
        unsigned short* Vt = (unsigned short*)Ovt;
#pragma unroll
        for (int nt = 0; nt < 8; nt++) {
            const int col = bn + nt * 16 + l16;
            const float bv_ = bias[col];
            uint2 pk;
            pk.x = pk2(acc[nt][0] + bv_, acc[nt][1] + bv_);
            pk.y = pk2(acc[nt][2] + bv_, acc[nt][3] + bv_);
            *(uint2*)&Vt[((size_t)(b * 512 + col)) * 4096 + seq0] = pk;
        }
    } else {
        unsigned short* C = (unsigned short*)((z == 0) ? Oq : Ok);
        const float scale = (z == 0) ? QSCALE : 1.0f;
        const size_t row0 = bm + wave * 16 + quad * 4;
#pragma unroll
        for (int nt = 0; nt < 8; nt++) {
            const int col = bn + nt * 16 + l16;
            const float bv_ = bias[col];
            unsigned u01 = pk2((acc[nt][0] + bv_) * scale, (acc[nt][1] + bv_) * scale);
            unsigned u23 = pk2((acc[nt][2] + bv_) * scale, (acc[nt][3] + bv_) * scale);
            C[(row0 + 0) * DM + col] = (unsigned short)(u01 & 0xffff);
            C[(row0 + 1) * DM + col] = (unsigned short)(u01 >> 16);
            C[(row0 + 2) * DM + col] = (unsigned short)(u23 & 0xffff);
            C[(row0 + 3) * DM + col] = (unsigned short)(u23 >> 16);
        }
    }
}

// Flash attention, transposed-S, fixed-shift log2 softmax.
// R11: each wave owns 32 q (two 16-q groups qh=0/1); block = 128 q.
// Ks fragments + av fragments + staging + barriers shared across both halves.
__global__ __launch_bounds__(256) void flash_attn(
    const __hip_bfloat16* __restrict__ Q,
    const __hip_bfloat16* __restrict__ K,
    const __hip_bfloat16* __restrict__ Vt,
    __hip_bfloat16* __restrict__ O)
{
    __shared__ __align__(16) short Qs[128 * FPAD];     // [q][d]; reused as Ps after hoist
    __shared__ __align__(16) short Ks[64 * FPAD];      // [kv][d]
    __shared__ __align__(16) short Vs[64 * FPAD];      // [dv][kv] (pre-transposed)
    // Ps alias: wave w's strip = Qs rows [w*32, w*32+32) — exactly the Q rows only
    // wave w reads (hoisted into regs before first Ps write; same-wave DS ordered).
    short (*Ps)[32 * FPAD] = (short(*)[32 * FPAD])Qs;

    const int q0 = blockIdx.x * 128;
    const int bh = blockIdx.y;

    const int tid  = threadIdx.x;
    const int wave = tid >> 6;
    const int lane = tid & 63;
    const int quad = lane >> 4;
    const int l16  = lane & 15;
    const int qw   = wave * 32;     // wave's q base within block

    const __hip_bfloat16* Qb = Q + (size_t)(bh >> 3) * SEQ * DM + (bh & 7) * 64;
    const __hip_bfloat16* Kb = K + (size_t)(bh >> 3) * SEQ * DM + (bh & 7) * 64;
    const __hip_bfloat16* Vb = Vt + (size_t)bh * 64 * SEQ;
    __hip_bfloat16*       Ob = O + (size_t)(bh >> 3) * SEQ * DM + (bh & 7) * 64;

    const int r0 = tid >> 3;        // 0..31
    const int c8 = (tid & 7) * 8;

    // Q stage (once): 128 rows x 64 cols, 4 rows/thread
#pragma unroll
    for (int i = 0; i < 4; i++)
        *(bf16x8*)&Qs[(r0 + i * 32) * FPAD + c8] =
            *(const bf16x8*)&Qb[(size_t)(q0 + r0 + i * 32) * DM + c8];

    // prefetch kv tile 0
    bf16x8 kp0 = *(const bf16x8*)&Kb[(size_t)r0 * DM + c8];
    bf16x8 kp1 = *(const bf16x8*)&Kb[(size_t)(r0 + 32) * DM + c8];
    bf16x8 vp0 = *(const bf16x8*)&Vb[(size_t)r0 * SEQ + c8];
    bf16x8 vp1 = *(const bf16x8*)&Vb[(size_t)(r0 + 32) * SEQ + c8];

    __syncthreads();   // Qs staged

    // hoist loop-invariant Q B-frags: bq[qh][ks], q = qw + qh*16 + l16
    bf16x8 bq[2][2];
#pragma unroll
    for (int qh = 0; qh < 2; qh++)
#pragma unroll
        for (int ks = 0; ks < 2; ks++)
            bq[qh][ks] = *(bf16x8*)&Qs[(qw + qh * 16 + l16) * FPAD + ks * 32 + quad * 8];

    bf16x8 ones;
#pragma unroll
    for (int j = 0; j < 8; j++) ones[j] = (short)0x3F80;

    f32x4 oacc[2][4] = {};   // O^T per qh: lane holds (dv = dt*16+quad*4+r, q)
    f32x4 lacc[2] = {};      // per-qh denominator (ones-MFMA row sums)

    for (int kv0 = 0; kv0 < SEQ; kv0 += 64) {
        __syncthreads();
        *(bf16x8*)&Ks[r0 * FPAD + c8] = kp0;
        *(bf16x8*)&Ks[(r0 + 32) * FPAD + c8] = kp1;
        *(bf16x8*)&Vs[r0 * FPAD + c8] = vp0;
        *(bf16x8*)&Vs[(r0 + 32) * FPAD + c8] = vp1;
        __syncthreads();

        if (kv0 + 64 < SEQ) {   // prefetch next tile; overlaps softmax + PV
            kp0 = *(const bf16x8*)&Kb[(size_t)(kv0 + 64 + r0) * DM + c8];
            kp1 = *(const bf16x8*)&Kb[(size_t)(kv0 + 96 + r0) * DM + c8];
            vp0 = *(const bf16x8*)&Vb[(size_t)r0 * SEQ + kv0 + 64 + c8];
            vp1 = *(const bf16x8*)&Vb[(size_t)(r0 + 32) * SEQ + kv0 + 64 + c8];
        }

        // S^T = K Q^T: Ks frags shared across both q-halves
        f32x4 s[2][4] = {};
#pragma unroll
        for (int ks = 0; ks < 2; ks++) {
#pragma unroll
            for (int nt = 0; nt < 4; nt++) {
                bf16x8 ak = *(bf16x8*)&Ks[(nt * 16 + l16) * FPAD + ks * 32 + quad * 8];
#pragma unroll
                for (int qh = 0; qh < 2; qh++)
                    s[qh][nt] = __builtin_amdgcn_mfma_f32_16x16x32_bf16(
                        ak, bq[qh][ks], s[qh][nt], 0, 0, 0);
            }
        }

        // P = 2^(s - 16): exact by shift-invariance; no max, no rescale
#pragma unroll
        for (int qh = 0; qh < 2; qh++) {
#pragma unroll
            for (int nt = 0; nt < 4; nt++) {
                float p0 = fast_exp2(s[qh][nt][0] - FSHIFT);
                float p1 = fast_exp2(s[qh][nt][1] - FSHIFT);
                float p2 = fast_exp2(s[qh][nt][2] - FSHIFT);
                float p3 = fast_exp2(s[qh][nt][3] - FSHIFT);
                uint2 pk;
                pk.x = pk2(p0, p1);
                pk.y = pk2(p2, p3);
                *(uint2*)&Ps[wave][(qh * 16 + l16) * FPAD + nt * 16 + quad * 4] = pk;
            }
        }

        // O^T += V^T P^T; l += ones P^T. av frags cached, shared across q-halves.
#pragma unroll
        for (int ks = 0; ks < 2; ks++) {
            bf16x8 av[4];
#pragma unroll
            for (int dt = 0; dt < 4; dt++)
                av[dt] = *(bf16x8*)&Vs[(dt * 16 + l16) * FPAD + ks * 32 + quad * 8];
#pragma unroll
            for (int qh = 0; qh < 2; qh++) {
                bf16x8 bp = *(bf16x8*)&Ps[wave][(qh * 16 + l16) * FPAD + ks * 32 + quad * 8];
#pragma unroll
                for (int dt = 0; dt < 4; dt++)
                    oacc[qh][dt] = __builtin_amdgcn_mfma_f32_16x16x32_bf16(
                        av[dt], bp, oacc[qh][dt], 0, 0, 0);
                lacc[qh] = __builtin_amdgcn_mfma_f32_16x16x32_bf16(ones, bp, lacc[qh], 0, 0, 0);
            }
        }
    }

    // epilogue: lane owns q = q0 + qw + qh*16 + l16; 4 consecutive dv per dt
    unsigned short* Op = (unsigned short*)Ob;
#pragma unroll
    for (int qh = 0; qh < 2; qh++) {
        const float inv = 1.0f / lacc[qh][0];
        const int q = q0 + qw + qh * 16 + l16;
#pragma unroll
        for (int dt = 0; dt < 4; dt++) {
            uint2 ov;
            ov.x = pk2(oacc[qh][dt][0] * inv, oacc[qh][dt][1] * inv);
            ov.y = pk2(oacc[qh][dt][2] * inv, oacc[qh][dt][3] * inv);
            *(uint2*)&Op[(size_t)q * DM + dt * 16 + quad * 4] = ov;
        }
    }
}

// Output projection (R9 structure), 64x128 tile: A bf16, W bf16, C fp32.
__global__ __launch_bounds__(256) void out_proj(
    const __hip_bfloat16* __restrict__ A,
    const __hip_bfloat16* __restrict__ W,
    const float* __restrict__ bias,
    float* __restrict__ C)
{
    __shared__ __align__(16) short As[64 * 32];
    __shared__ __align__(16) short Ws2[128 * 32];

    const int bm   = blockIdx.x * 64;
    const int bn   = blockIdx.y * 128;
    const int tid  = threadIdx.x;
    const int wave = tid >> 6;
    const int lane = tid & 63;
    const int quad = lane >> 4;
    const int l16  = lane & 15;

    const int srow = tid >> 2;
    const int scol = (tid & 3) * 8;

    f32x4 acc[8] = {};

    bf16x8 ap = *(const bf16x8*)&A[(size_t)(bm + srow) * DM + scol];
    bf16x8 w0 = *(const bf16x8*)&W[(size_t)(bn + srow) * DM + scol];
    bf16x8 w1 = *(const bf16x8*)&W[(size_t)(bn + srow + 64) * DM + scol];

    for (int k0 = 0; k0 < DM; k0 += 32) {
        __syncthreads();
        *(bf16x8*)&As[srow * 32 + scol] = ap;
        *(bf16x8*)&Ws2[srow * 32 + scol] = w0;
        *(bf16x8*)&Ws2[(srow + 64) * 32 + scol] = w1;
        __syncthreads();

        if (k0 + 32 < DM) {
            ap = *(const bf16x8*)&A[(size_t)(bm + srow) * DM + k0 + 32 + scol];
            w0 = *(const bf16x8*)&W[(size_t)(bn + srow) * DM + k0 + 32 + scol];
            w1 = *(const bf16x8*)&W[(size_t)(bn + srow + 64) * DM + k0 + 32 + scol];
        }

        bf16x8 a = *(bf16x8*)&As[(wave * 16 + l16) * 32 + quad * 8];
#pragma unroll
        for (int nt = 0; nt < 8; nt++) {
            bf16x8 b = *(bf16x8*)&Ws2[(nt * 16 + l16) * 32 + quad * 8];
            acc[nt] = __builtin_amdgcn_mfma_f32_16x16x32_bf16(a, b, acc[nt], 0, 0, 0);
        }
    }

#pragma unroll
    for (int nt = 0; nt < 8; nt++) {
        const int col = bn + nt * 16 + l16;
        const float bv_ = bias[col];
#pragma unroll
        for (int r = 0; r < 4; r++) {
            const int row = bm + wave * 16 + quad * 4 + r;
            C[(size_t)row * DM + col] = acc[nt][r] + bv_;
        }
    }
}

extern "C" void kernel_launch(void* const* d_in, const int* in_sizes, int n_in,
                              void* d_out, int out_size, void* d_ws, size_t ws_size,
                              hipStream_t stream) {
    const float* queries = (const float*)d_in[0];
    const float* keys    = (const float*)d_in[1];
    const float* values  = (const float*)d_in[2];
    const float* Wq = (const float*)d_in[3];
    const float* bq = (const float*)d_in[4];
    const float* Wk = (const float*)d_in[5];
    const float* bk = (const float*)d_in[6];
    const float* Wv = (const float*)d_in[7];
    const float* bv = (const float*)d_in[8];
    const float* Wo = (const float*)d_in[9];
    const float* bo = (const float*)d_in[10];
    float* out = (float*)d_out;

    const size_t MS = (size_t)2 * SEQ * DM;   // 4.19M elems
    const size_t WN = (size_t)DM * DM;        // 262144 elems
    __hip_bfloat16* q_ws  = (__hip_bfloat16*)d_ws;
    __hip_bfloat16* k_ws  = q_ws + MS;
    __hip_bfloat16* vt_ws = k_ws + MS;        // [16][64][4096]
    __hip_bfloat16* o_ws  = vt_ws + MS;
    __hip_bfloat16* wq16  = o_ws + MS;
    __hip_bfloat16* wk16  = wq16 + WN;
    __hip_bfloat16* wv16  = wk16 + WN;
    __hip_bfloat16* wo16  = wv16 + WN;

    dim3 blk(256);

    cvt_w<<<dim3(256, 4), blk, 0, stream>>>(Wq, Wk, Wv, Wo, wq16, wk16, wv16, wo16);

    qkv_proj<<<dim3(128, 4, 3), blk, 0, stream>>>(
        queries, keys, values, wq16, wk16, wv16, bq, bk, bv, q_ws, k_ws, vt_ws);

    flash_attn<<<dim3(32, 16), blk, 0, stream>>>(q_ws, k_ws, vt_ws, o_ws);

    out_proj<<<dim3(128, 4), blk, 0, stream>>>(o_ws, wo16, bo, out);
}

// Round 12
// 261.216 us; speedup vs baseline: 1.0544x; 1.0116x over previous
//
#include <hip/hip_runtime.h>
#include <hip/hip_bf16.h>

// MHA: weight pre-convert -> fused qkv proj (R9/R11 64x128) -> flash attention
// (transposed-S, fixed-shift log2 softmax, ones-MFMA denominator, 32 q/wave,
// KV-TILE 128 with per-64 sub-tiling, hoisted LDS bases, running global ptrs)
// -> out proj. R12: flash loop-overhead cut; GEMMs untouched (control).

typedef __attribute__((ext_vector_type(8))) short bf16x8;   // 8 bf16 (MFMA A/B frag)
typedef __attribute__((ext_vector_type(4))) float f32x4;    // MFMA C/D frag

#define SEQ  4096
#define DM   512
#define FPAD 72    // Qs/Ks/Ps row stride (shorts)
#define VPAD 136   // Vs row stride (shorts): 64 dv x 128 kv + pad
#define QSCALE 0.18033688011112042f   // 0.125 * log2(e): scores in log2 domain
#define FSHIFT 16.0f                  // fixed softmax shift (log2 domain)

__device__ inline float fast_exp2(float x) {   // raw v_exp_f32: D = 2^S0
#if __has_builtin(__builtin_amdgcn_exp2f)
    return __builtin_amdgcn_exp2f(x);
#else
    return __expf(x * 0.69314718056f);
#endif
}

__device__ inline unsigned pk2(float x, float y) {   // 2x f32 -> packed bf16 RNE
#if __has_builtin(__builtin_amdgcn_cvt_pk_bf16_f32)
    typedef __attribute__((ext_vector_type(2))) __bf16 bf16x2_t;
    bf16x2_t h = __builtin_amdgcn_cvt_pk_bf16_f32(x, y);
    return *(unsigned*)&h;
#else
    unsigned ux = __float_as_uint(x);
    unsigned uy = __float_as_uint(y);
    ux += 0x7fff + ((ux >> 16) & 1);      // finite-safe RNE (all inputs finite)
    uy += 0x7fff + ((uy >> 16) & 1);
    return (ux >> 16) | (uy & 0xffff0000u);
#endif
}

// Convert the 4 weight matrices (512x512 fp32) to bf16 once.
__global__ __launch_bounds__(256) void cvt_w(
    const float* __restrict__ w0, const float* __restrict__ w1,
    const float* __restrict__ w2, const float* __restrict__ w3,
    __hip_bfloat16* __restrict__ o0, __hip_bfloat16* __restrict__ o1,
    __hip_bfloat16* __restrict__ o2, __hip_bfloat16* __restrict__ o3)
{
    const float* w = (blockIdx.y == 0) ? w0 : (blockIdx.y == 1) ? w1
                   : (blockIdx.y == 2) ? w2 : w3;
    __hip_bfloat16* o = (blockIdx.y == 0) ? o0 : (blockIdx.y == 1) ? o1
                      : (blockIdx.y == 2) ? o2 : o3;
    const int i = (blockIdx.x * 256 + threadIdx.x) * 4;   // < 262144
    float4 v = *(const float4*)&w[i];
    uint2 p;
    p.x = pk2(v.x, v.y);
    p.y = pk2(v.z, v.w);
    *(uint2*)&((unsigned short*)o)[i] = p;
}

// Fused QKV projection (R9 structure), 64(M) x 128(N) tile, z selects stream.
__global__ __launch_bounds__(256) void qkv_proj(
    const float* __restrict__ Xq, const float* __restrict__ Xk, const float* __restrict__ Xv,
    const __hip_bfloat16* __restrict__ Wq16, const __hip_bfloat16* __restrict__ Wk16,
    const __hip_bfloat16* __restrict__ Wv16,
    const float* __restrict__ bq, const float* __restrict__ bk, const float* __restrict__ bv,
    __hip_bfloat16* __restrict__ Oq, __hip_bfloat16* __restrict__ Ok,
    __hip_bfloat16* __restrict__ Ovt)
{
    const int z = blockIdx.z;
    const float* A          = (z == 0) ? Xq : (z == 1) ? Xk : Xv;
    const __hip_bfloat16* W = (z == 0) ? Wq16 : (z == 1) ? Wk16 : Wv16;
    const float* bias       = (z == 0) ? bq : (z == 1) ? bk : bv;

    __shared__ __align__(16) short As[64 * 32];
    __shared__ __align__(16) short Ws2[128 * 32];

    const int bm   = blockIdx.x * 64;
    const int bn   = blockIdx.y * 128;
    const int tid  = threadIdx.x;
    const int wave = tid >> 6;
    const int lane = tid & 63;
    const int quad = lane >> 4;
    const int l16  = lane & 15;

    const int srow = tid >> 2;          // 0..63
    const int scol = (tid & 3) * 8;     // 0/8/16/24

    f32x4 acc[8] = {};

    float4 a0 = *(const float4*)&A[(size_t)(bm + srow) * DM + scol];
    float4 a1 = *(const float4*)&A[(size_t)(bm + srow) * DM + scol + 4];
    bf16x8 w0 = *(const bf16x8*)&W[(size_t)(bn + srow) * DM + scol];
    bf16x8 w1 = *(const bf16x8*)&W[(size_t)(bn + srow + 64) * DM + scol];

    for (int k0 = 0; k0 < DM; k0 += 32) {
        uint4 pa = {pk2(a0.x, a0.y), pk2(a0.z, a0.w), pk2(a1.x, a1.y), pk2(a1.z, a1.w)};

        __syncthreads();
        *(uint4*)&As[srow * 32 + scol] = pa;
        *(bf16x8*)&Ws2[srow * 32 + scol] = w0;
        *(bf16x8*)&Ws2[(srow + 64) * 32 + scol] = w1;
        __syncthreads();

        if (k0 + 32 < DM) {
            a0 = *(const float4*)&A[(size_t)(bm + srow) * DM + k0 + 32 + scol];
            a1 = *(const float4*)&A[(size_t)(bm + srow) * DM + k0 + 32 + scol + 4];
            w0 = *(const bf16x8*)&W[(size_t)(bn + srow) * DM + k0 + 32 + scol];
            w1 = *(const bf16x8*)&W[(size_t)(bn + srow + 64) * DM + k0 + 32 + scol];
        }

        bf16x8 a = *(bf16x8*)&As[(wave * 16 + l16) * 32 + quad * 8];
#pragma unroll
        for (int nt = 0; nt < 8; nt++) {
            bf16x8 b = *(bf16x8*)&Ws2[(nt * 16 + l16) * 32 + quad * 8];
            acc[nt] = __builtin_amdgcn_mfma_f32_16x16x32_bf16(a, b, acc[nt], 0, 0, 0);
        }
    }

    // C/D layout: col = lane&15 (= n), row = quad*4 + r (= m)
    if (z == 2) {
        const int row0 = bm + wave * 16 + quad * 4;
        const int b    = row0 >> 12;
        const int seq0 = row0 & 4095;
        unsigned short* Vt = (unsigned short*)Ovt;
#pragma unroll
        for (int nt = 0; nt < 8; nt++) {
            const int col = bn + nt * 16 + l16;
            const float bv_ = bias[col];
            uint2 pk;
            pk.x = pk2(acc[nt][0] + bv_, acc[nt][1] + bv_);
            pk.y = pk2(acc[nt][2] + bv_, acc[nt][3] + bv_);
            *(uint2*)&Vt[((size_t)(b * 512 + col)) * 4096 + seq0] = pk;
        }
    } else {
        unsigned short* C = (unsigned short*)((z == 0) ? Oq : Ok);
        const float scale = (z == 0) ? QSCALE : 1.0f;
        const size_t row0 = bm + wave * 16 + quad * 4;
#pragma unroll
        for (int nt = 0; nt < 8; nt++) {
            const int col = bn + nt * 16 + l16;
            const float bv_ = bias[col];
            unsigned u01 = pk2((acc[nt][0] + bv_) * scale, (acc[nt][1] + bv_) * scale);
            unsigned u23 = pk2((acc[nt][2] + bv_) * scale, (acc[nt][3] + bv_) * scale);
            C[(row0 + 0) * DM + col] = (unsigned short)(u01 & 0xffff);
            C[(row0 + 1) * DM + col] = (unsigned short)(u01 >> 16);
            C[(row0 + 2) * DM + col] = (unsigned short)(u23 & 0xffff);
            C[(row0 + 3) * DM + col] = (unsigned short)(u23 >> 16);
        }
    }
}

// Flash attention: transposed-S, fixed-shift log2 softmax, 32 q/wave,
// KV tile = 128 (two 64-kv sub-tiles sharing one staging round + barrier pair).
__global__ __launch_bounds__(256) void flash_attn(
    const __hip_bfloat16* __restrict__ Q,
    const __hip_bfloat16* __restrict__ K,
    const __hip_bfloat16* __restrict__ Vt,
    __hip_bfloat16* __restrict__ O)
{
    __shared__ __align__(16) short Qs[128 * FPAD];     // [q][d]; Ps aliases per-wave strips
    __shared__ __align__(16) short Ks[128 * FPAD];     // [kv 128][d]
    __shared__ __align__(16) short Vs[64 * VPAD];      // [dv][kv 128] (pre-transposed)
    short (*Ps)[32 * FPAD] = (short(*)[32 * FPAD])Qs;  // wave w strip = Qs rows [w*32, w*32+32)

    const int q0 = blockIdx.x * 128;
    const int bh = blockIdx.y;

    const int tid  = threadIdx.x;
    const int wave = tid >> 6;
    const int lane = tid & 63;
    const int quad = lane >> 4;
    const int l16  = lane & 15;
    const int qw   = wave * 32;     // wave's q base within block

    const __hip_bfloat16* Qb = Q + (size_t)(bh >> 3) * SEQ * DM + (bh & 7) * 64;
    const __hip_bfloat16* Kb = K + (size_t)(bh >> 3) * SEQ * DM + (bh & 7) * 64;
    const __hip_bfloat16* Vb = Vt + (size_t)bh * 64 * SEQ;
    __hip_bfloat16*       Ob = O + (size_t)(bh >> 3) * SEQ * DM + (bh & 7) * 64;

    // staging maps
    const int kr = tid >> 3;            // 0..31: K rows kr + i*32, cols (tid&7)*8
    const int kc = (tid & 7) * 8;
    const int vr = tid >> 2;            // 0..63: V row vr, cols (tid&3)*8 + i*32
    const int vc = (tid & 3) * 8;

    // Q stage (once): 128 rows
#pragma unroll
    for (int i = 0; i < 4; i++)
        *(bf16x8*)&Qs[(kr + i * 32) * FPAD + kc] =
            *(const bf16x8*)&Qb[(size_t)(q0 + kr + i * 32) * DM + kc];

    // running global prefetch pointers (advance by constants)
    const __hip_bfloat16* kg = Kb + (size_t)kr * DM + kc;
    const __hip_bfloat16* vg = Vb + (size_t)vr * SEQ + vc;

    bf16x8 kp[4], vp[4];
#pragma unroll
    for (int i = 0; i < 4; i++) {
        kp[i] = *(const bf16x8*)(kg + (size_t)i * 32 * DM);
        vp[i] = *(const bf16x8*)(vg + i * 32);
    }

    __syncthreads();   // Qs staged

    // hoist loop-invariant Q B-frags: bq[qh][ks], q = qw + qh*16 + l16
    bf16x8 bq[2][2];
#pragma unroll
    for (int qh = 0; qh < 2; qh++)
#pragma unroll
        for (int ks = 0; ks < 2; ks++)
            bq[qh][ks] = *(bf16x8*)&Qs[(qw + qh * 16 + l16) * FPAD + ks * 32 + quad * 8];

    bf16x8 ones;
#pragma unroll
    for (int j = 0; j < 8; j++) ones[j] = (short)0x3F80;

    // hoisted LDS base pointers (constant offsets inside the loop)
    const short* ksb = &Ks[l16 * FPAD + quad * 8];
    const short* vsb = &Vs[l16 * VPAD + quad * 8];
    const short* psb = &Ps[wave][l16 * FPAD + quad * 8];   // bp reads
    short*       psw = &Ps[wave][l16 * FPAD + quad * 4];   // P writes

    f32x4 oacc[2][4] = {};   // O^T per qh
    f32x4 lacc[2] = {};      // per-qh denominator

    for (int kv0 = 0; kv0 < SEQ; kv0 += 128) {
        __syncthreads();
#pragma unroll
        for (int i = 0; i < 4; i++) {
            *(bf16x8*)&Ks[(kr + i * 32) * FPAD + kc] = kp[i];
            *(bf16x8*)&Vs[vr * VPAD + vc + i * 32] = vp[i];
        }
        __syncthreads();

        kg += (size_t)128 * DM;
        vg += 128;
        if (kv0 + 128 < SEQ) {
#pragma unroll
            for (int i = 0; i < 4; i++) {
                kp[i] = *(const bf16x8*)(kg + (size_t)i * 32 * DM);
                vp[i] = *(const bf16x8*)(vg + i * 32);
            }
        }

#pragma unroll
        for (int kh = 0; kh < 2; kh++) {
            // S^T = K Q^T for this 64-kv half
            f32x4 s[2][4] = {};
#pragma unroll
            for (int ks = 0; ks < 2; ks++) {
#pragma unroll
                for (int nt = 0; nt < 4; nt++) {
                    bf16x8 ak = *(const bf16x8*)&ksb[(kh * 64 + nt * 16) * FPAD + ks * 32];
#pragma unroll
                    for (int qh = 0; qh < 2; qh++)
                        s[qh][nt] = __builtin_amdgcn_mfma_f32_16x16x32_bf16(
                            ak, bq[qh][ks], s[qh][nt], 0, 0, 0);
                }
            }

            // P = 2^(s - 16): exact by shift-invariance
#pragma unroll
            for (int qh = 0; qh < 2; qh++) {
#pragma unroll
                for (int nt = 0; nt < 4; nt++) {
                    float p0 = fast_exp2(s[qh][nt][0] - FSHIFT);
                    float p1 = fast_exp2(s[qh][nt][1] - FSHIFT);
                    float p2 = fast_exp2(s[qh][nt][2] - FSHIFT);
                    float p3 = fast_exp2(s[qh][nt][3] - FSHIFT);
                    uint2 pk;
                    pk.x = pk2(p0, p1);
                    pk.y = pk2(p2, p3);
                    *(uint2*)&psw[qh * 16 * FPAD + nt * 16] = pk;
                }
            }

            // O^T += V^T P^T; l += ones P^T  (Ps per-wave; lgkmcnt orders same-wave DS)
#pragma unroll
            for (int ks = 0; ks < 2; ks++) {
                bf16x8 av[4];
#pragma unroll
                for (int dt = 0; dt < 4; dt++)
                    av[dt] = *(const bf16x8*)&vsb[dt * 16 * VPAD + kh * 64 + ks * 32];
#pragma unroll
                for (int qh = 0; qh < 2; qh++) {
                    bf16x8 bp = *(const bf16x8*)&psb[qh * 16 * FPAD + ks * 32];
#pragma unroll
                    for (int dt = 0; dt < 4; dt++)
                        oacc[qh][dt] = __builtin_amdgcn_mfma_f32_16x16x32_bf16(
                            av[dt], bp, oacc[qh][dt], 0, 0, 0);
                    lacc[qh] = __builtin_amdgcn_mfma_f32_16x16x32_bf16(
                        ones, bp, lacc[qh], 0, 0, 0);
                }
            }
        }
    }

    // epilogue: lane owns q = q0 + qw + qh*16 + l16; 4 consecutive dv per dt
    unsigned short* Op = (unsigned short*)Ob;
#pragma unroll
    for (int qh = 0; qh < 2; qh++) {
        const float inv = 1.0f / lacc[qh][0];
        const int q = q0 + qw + qh * 16 + l16;
#pragma unroll
        for (int dt = 0; dt < 4; dt++) {
            uint2 ov;
            ov.x = pk2(oacc[qh][dt][0] * inv, oacc[qh][dt][1] * inv);
            ov.y = pk2(oacc[qh][dt][2] * inv, oacc[qh][dt][3] * inv);
            *(uint2*)&Op[(size_t)q * DM + dt * 16 + quad * 4] = ov;
        }
    }
}

// Output projection (R9 structure), 64x128 tile: A bf16, W bf16, C fp32.
__global__ __launch_bounds__(256) void out_proj(
    const __hip_bfloat16* __restrict__ A,
    const __hip_bfloat16* __restrict__ W,
    const float* __restrict__ bias,
    float* __restrict__ C)
{
    __shared__ __align__(16) short As[64 * 32];
    __shared__ __align__(16) short Ws2[128 * 32];

    const int bm   = blockIdx.x * 64;
    const int bn   = blockIdx.y * 128;
    const int tid  = threadIdx.x;
    const int wave = tid >> 6;
    const int lane = tid & 63;
    const int quad = lane >> 4;
    const int l16  = lane & 15;

    const int srow = tid >> 2;
    const int scol = (tid & 3) * 8;

    f32x4 acc[8] = {};

    bf16x8 ap = *(const bf16x8*)&A[(size_t)(bm + srow) * DM + scol];
    bf16x8 w0 = *(const bf16x8*)&W[(size_t)(bn + srow) * DM + scol];
    bf16x8 w1 = *(const bf16x8*)&W[(size_t)(bn + srow + 64) * DM + scol];

    for (int k0 = 0; k0 < DM; k0 += 32) {
        __syncthreads();
        *(bf16x8*)&As[srow * 32 + scol] = ap;
        *(bf16x8*)&Ws2[srow * 32 + scol] = w0;
        *(bf16x8*)&Ws2[(srow + 64) * 32 + scol] = w1;
        __syncthreads();

        if (k0 + 32 < DM) {
            ap = *(const bf16x8*)&A[(size_t)(bm + srow) * DM + k0 + 32 + scol];
            w0 = *(const bf16x8*)&W[(size_t)(bn + srow) * DM + k0 + 32 + scol];
            w1 = *(const bf16x8*)&W[(size_t)(bn + srow + 64) * DM + k0 + 32 + scol];
        }

        bf16x8 a = *(bf16x8*)&As[(wave * 16 + l16) * 32 + quad * 8];
#pragma unroll
        for (int nt = 0; nt < 8; nt++) {
            bf16x8 b = *(bf16x8*)&Ws2[(nt * 16 + l16) * 32 + quad * 8];
            acc[nt] = __builtin_amdgcn_mfma_f32_16x16x32_bf16(a, b, acc[nt], 0, 0, 0);
        }
    }

#pragma unroll
    for (int nt = 0; nt < 8; nt++) {
        const int col = bn + nt * 16 + l16;
        const float bv_ = bias[col];
#pragma unroll
        for (int r = 0; r < 4; r++) {
            const int row = bm + wave * 16 + quad * 4 + r;
            C[(size_t)row * DM + col] = acc[nt][r] + bv_;
        }
    }
}

extern "C" void kernel_launch(void* const* d_in, const int* in_sizes, int n_in,
                              void* d_out, int out_size, void* d_ws, size_t ws_size,
                              hipStream_t stream) {
    const float* queries = (const float*)d_in[0];
    const float* keys    = (const float*)d_in[1];
    const float* values  = (const float*)d_in[2];
    const float* Wq = (const float*)d_in[3];
    const float* bq = (const float*)d_in[4];
    const float* Wk = (const float*)d_in[5];
    const float* bk = (const float*)d_in[6];
    const float* Wv = (const float*)d_in[7];
    const float* bv = (const float*)d_in[8];
    const float* Wo = (const float*)d_in[9];
    const float* bo = (const float*)d_in[10];
    float* out = (float*)d_out;

    const size_t MS = (size_t)2 * SEQ * DM;   // 4.19M elems
    const size_t WN = (size_t)DM * DM;        // 262144 elems
    __hip_bfloat16* q_ws  = (__hip_bfloat16*)d_ws;
    __hip_bfloat16* k_ws  = q_ws + MS;
    __hip_bfloat16* vt_ws = k_ws + MS;        // [16][64][4096]
    __hip_bfloat16* o_ws  = vt_ws + MS;
    __hip_bfloat16* wq16  = o_ws + MS;
    __hip_bfloat16* wk16  = wq16 + WN;
    __hip_bfloat16* wv16  = wk16 + WN;
    __hip_bfloat16* wo16  = wv16 + WN;

    dim3 blk(256);

    cvt_w<<<dim3(256, 4), blk, 0, stream>>>(Wq, Wk, Wv, Wo, wq16, wk16, wv16, wo16);

    qkv_proj<<<dim3(128, 4, 3), blk, 0, stream>>>(
        queries, keys, values, wq16, wk16, wv16, bq, bk, bv, q_ws, k_ws, vt_ws);

    flash_attn<<<dim3(32, 16), blk, 0, stream>>>(q_ws, k_ws, vt_ws, o_ws);

    out_proj<<<dim3(128, 4), blk, 0, stream>>>(o_ws, wo16, bo, out);
}